// Round 12
// baseline (107.811 us; speedup 1.0000x reference)
//
#include <hip/hip_runtime.h>
#include <hip/hip_bf16.h>

// loss = (1/N) * [ sum_i softplus(-s_ii) + sum_{i!=j} softplus(s_ij) ] + ln2
// S = E E^T, N=16384, D=128.
// E pre-scaled by sqrt(log2e), cast to fp8 e4m3 in a k-tiled layout; scores
// come out in log2 domain: softplus*log2e = max(v,0) + log2(1+2^-|v|)
// ~= max(v,0) + u*(QC0+QC1*u), u = 2^-|v|.
// ROUND 12: A-resident row-walk. 768 persistent blocks (3/CU, 48KiB LDS =
// A + 2xB dbuf), each walks ~11 contiguous triangular tiles; A restaged only
// on row change (rare). Counted vmcnt(2) same-row / vmcnt(0) row-change.
// Last-block-done finalize (768 counter atomics total). fp8 MFMA 16x16x32,
// fused epilogue, 1 accum atomic/block.
// fp8 tiled layout per 128-row slab (16KB): elem (r,k): kb=k/8, g=kb&3,
// s=kb>>2 -> byte (g*2+(s>>1))*2048 + r*16 + (s&1)*8 + (k&7). Read: b128 at
// (kgrp*2+ks2)*2048 + row*16 = lane's 8 fp8 for two K-slices (lo/hi long).

#define N_DOCS 16384
#define DIM 128
#define NTILE 128                      // N_DOCS / 128
#define NTRI (NTILE * (NTILE + 1) / 2) // 8256
#define PBLOCKS 768                    // persistent blocks, 3 per CU

typedef __attribute__((ext_vector_type(4))) float f32x4;
typedef __attribute__((ext_vector_type(8))) __bf16 bf16x8;   // fallback path
typedef __attribute__((ext_vector_type(2))) long longx2;

typedef const __attribute__((address_space(1))) unsigned char* gptr_t;
typedef __attribute__((address_space(3))) unsigned char* lptr_t;

#define SQRT_LOG2E 1.2011224087864498f
#define LN2F 0.6931471805599453f
// log2(1+u) ~= u*(QC0 + QC1*u) on [0,1]
#define QC0 1.33985f
#define QC1 (-0.33985f)

#if __has_builtin(__builtin_amdgcn_exp2f)
#define EXP2F(x) __builtin_amdgcn_exp2f(x)
#else
#define EXP2F(x) exp2f(x)
#endif

#define BARRIER() do { asm volatile("" ::: "memory"); \
                       __builtin_amdgcn_s_barrier();  \
                       asm volatile("" ::: "memory"); } while (0)

__device__ __forceinline__ unsigned short f2bf(float f) {
  unsigned int u = __float_as_uint(f);
  u += 0x7fffu + ((u >> 16) & 1u);
  return (unsigned short)(u >> 16);
}

#if __has_builtin(__builtin_amdgcn_cvt_pk_fp8_f32)
#define HAVE_CVT_FP8 1
#else
__device__ __forceinline__ unsigned char f2e4m3(float x) {
  unsigned int u = __float_as_uint(x);
  unsigned char sgn = (unsigned char)((u >> 31) << 7);
  float ax = fabsf(x);
  if (!(ax < 464.f)) return sgn | 0x7E;
  unsigned int ua = u & 0x7FFFFFFFu;
  int e = (int)(ua >> 23) - 127;
  if (e < -6) {
    float q = rintf(ax * 512.f);
    return sgn | (unsigned char)q;
  }
  unsigned int mant = ua & 0x7FFFFFu;
  unsigned int keep = mant >> 20;
  unsigned int rest = mant & 0xFFFFFu;
  keep += (rest > 0x80000u) || (rest == 0x80000u && (keep & 1u));
  unsigned int ee = (unsigned int)(e + 7);
  if (keep == 8u) { keep = 0u; ee++; }
  if (ee >= 16u) return sgn | 0x7E;
  return sgn | (unsigned char)((ee << 3) | keep);
}
#endif

__device__ __forceinline__ void tri_decode(int g, int& tr, int& tc) {
  int r = (int)((2 * NTILE + 1 -
                 sqrtf((float)((2 * NTILE + 1) * (2 * NTILE + 1)) - 8.0f * (float)g)) * 0.5f);
  while (r * NTILE - r * (r - 1) / 2 > g) --r;
  while ((r + 1) * NTILE - (r + 1) * r / 2 <= g) ++r;
  tr = r;
  tc = r + (g - (r * NTILE - r * (r - 1) / 2));
}

// f32 -> scaled fp8, k-tiled layout. One thread = one (row, kb) = 8 elements.
__global__ void cast_kernel(const float* __restrict__ in, unsigned char* __restrict__ out,
                            float* __restrict__ accum, unsigned int* __restrict__ counter) {
  int i = blockIdx.x * blockDim.x + threadIdx.x;  // [0, 262144)
  if (i == 0) { accum[0] = 0.f; *counter = 0u; }  // stream-ordered before loss
  int row = i >> 4, kb = i & 15;
  const float4* p = reinterpret_cast<const float4*>(in + (size_t)row * 128 + kb * 8);
  float4 a = p[0], b = p[1];
  int w0, w1;
#ifdef HAVE_CVT_FP8
  w0 = __builtin_amdgcn_cvt_pk_fp8_f32(a.x * SQRT_LOG2E, a.y * SQRT_LOG2E, 0, false);
  w0 = __builtin_amdgcn_cvt_pk_fp8_f32(a.z * SQRT_LOG2E, a.w * SQRT_LOG2E, w0, true);
  w1 = __builtin_amdgcn_cvt_pk_fp8_f32(b.x * SQRT_LOG2E, b.y * SQRT_LOG2E, 0, false);
  w1 = __builtin_amdgcn_cvt_pk_fp8_f32(b.z * SQRT_LOG2E, b.w * SQRT_LOG2E, w1, true);
#else
  w0 = (int)f2e4m3(a.x * SQRT_LOG2E) | ((int)f2e4m3(a.y * SQRT_LOG2E) << 8) |
       ((int)f2e4m3(a.z * SQRT_LOG2E) << 16) | ((int)f2e4m3(a.w * SQRT_LOG2E) << 24);
  w1 = (int)f2e4m3(b.x * SQRT_LOG2E) | ((int)f2e4m3(b.y * SQRT_LOG2E) << 8) |
       ((int)f2e4m3(b.z * SQRT_LOG2E) << 16) | ((int)f2e4m3(b.w * SQRT_LOG2E) << 24);
#endif
  int slab = row >> 7, r = row & 127, g = kb & 3, s = kb >> 2;
  int off = slab * 16384 + (g * 2 + (s >> 1)) * 2048 + r * 16 + (s & 1) * 8;
  *reinterpret_cast<int2*>(out + off) = make_int2(w0, w1);
}

__global__ __launch_bounds__(512, 6) void loss_persist(const unsigned char* __restrict__ ef8,
                                                       float* __restrict__ accum,
                                                       unsigned int* __restrict__ counter,
                                                       float* __restrict__ out) {
  __shared__ alignas(16) unsigned char Asl[16384];      // A slab (row-resident)
  __shared__ alignas(16) unsigned char Bsl[2][16384];   // B dbuf
  __shared__ float red[8];
  const int tid = threadIdx.x;
  const int p = blockIdx.x;
  const int g0 = (p * 43) >> 2;          // p * 8256/768 = p*10.75
  const int g1 = ((p + 1) * 43) >> 2;
  const int n = g1 - g0;                 // 10 or 11 tiles

  const int wid = tid >> 6;
  const int lane = tid & 63;
  const int wm = wid >> 2, wn = wid & 3;  // 2x4 waves: 64x32 output each
  const int lrow = lane & 15;
  const int kgrp = lane >> 4;

  auto stageA = [&](int t) {
    const unsigned char* s = ef8 + (size_t)t * 16384;
#pragma unroll
    for (int it = 0; it < 2; ++it) {
      int pp = (it * 512 + tid) * 16;
      __builtin_amdgcn_global_load_lds((gptr_t)(s + pp), (lptr_t)(Asl + pp), 16, 0, 0);
    }
  };
  auto stageB = [&](int t, int buf) {
    const unsigned char* s = ef8 + (size_t)t * 16384;
#pragma unroll
    for (int it = 0; it < 2; ++it) {
      int pp = (it * 512 + tid) * 16;
      __builtin_amdgcn_global_load_lds((gptr_t)(s + pp), (lptr_t)(Bsl[buf] + pp), 16, 0, 0);
    }
  };

  auto compute = [&](int buf, bool diag) -> float {
    const unsigned char* As = (const unsigned char*)Asl;
    const unsigned char* Bs = (const unsigned char*)Bsl[buf];

    f32x4 acc[4][2];
#pragma unroll
    for (int a = 0; a < 4; ++a)
#pragma unroll
      for (int c = 0; c < 2; ++c) acc[a][c] = (f32x4){0.f, 0.f, 0.f, 0.f};

#pragma unroll
    for (int ks2 = 0; ks2 < 2; ++ks2) {
      longx2 af[4], bf[2];
      const int pbase = (kgrp * 2 + ks2) * 2048;
#pragma unroll
      for (int f = 0; f < 4; ++f) {
        int ar = wm * 64 + f * 16 + lrow;
        af[f] = *reinterpret_cast<const longx2*>(As + pbase + ar * 16);
      }
#pragma unroll
      for (int f = 0; f < 2; ++f) {
        int br = wn * 32 + f * 16 + lrow;
        bf[f] = *reinterpret_cast<const longx2*>(Bs + pbase + br * 16);
      }
#pragma unroll
      for (int fm = 0; fm < 4; ++fm)
#pragma unroll
        for (int fn = 0; fn < 2; ++fn) {
          acc[fm][fn] = __builtin_amdgcn_mfma_f32_16x16x32_fp8_fp8(af[fm].x, bf[fn].x,
                                                                   acc[fm][fn], 0, 0, 0);
          acc[fm][fn] = __builtin_amdgcn_mfma_f32_16x16x32_fp8_fp8(af[fm].y, bf[fn].y,
                                                                   acc[fm][fn], 0, 0, 0);
        }
    }

    // epilogue, log2 domain. C/D layout: col=lane&15, row=(lane>>4)*4+reg.
    float sm = 0.f, sp = 0.f;
    if (diag) {
#pragma unroll
      for (int fm = 0; fm < 4; ++fm)
#pragma unroll
        for (int fn = 0; fn < 2; ++fn)
#pragma unroll
          for (int r = 0; r < 4; ++r) {
            float v = acc[fm][fn][r];
            int il = wm * 64 + fm * 16 + kgrp * 4 + r;
            int jl = wn * 32 + fn * 16 + lrow;
            if (il == jl) v = -v;
            sm += fmaxf(v, 0.f);
            float u = EXP2F(-fabsf(v));
            sp = fmaf(u, fmaf(u, QC1, QC0), sp);
          }
      return sm + sp;
    } else {
#pragma unroll
      for (int fm = 0; fm < 4; ++fm)
#pragma unroll
        for (int fn = 0; fn < 2; ++fn)
#pragma unroll
          for (int r = 0; r < 4; ++r) {
            float v = acc[fm][fn][r];
            sm += fmaxf(v, 0.f);
            float u = EXP2F(-fabsf(v));
            sp = fmaf(u, fmaf(u, QC1, QC0), sp);
          }
      return 2.f * (sm + sp);  // symmetric twin tile
    }
  };

  // ---- A-resident row-walk with B double-buffer ----
  int tr, tc;
  tri_decode(g0, tr, tc);
  float total = 0.f;
  int buf = 0;
  stageA(tr);
  stageB(tc, 0);
  for (int i = 0; i < n; ++i) {
    int ntr = tr, ntc = tc + 1;
    if (ntc == NTILE) { ntr = tr + 1; ntc = ntr; }
    const bool have_next = (i + 1 < n);
    const bool samerow = have_next && (ntr == tr);
    if (samerow) {
      stageB(ntc, buf ^ 1);                             // 2 loads in flight
      asm volatile("s_waitcnt vmcnt(2)" ::: "memory");  // tile i's loads landed
    } else {
      asm volatile("s_waitcnt vmcnt(0)" ::: "memory");
    }
    BARRIER();
    total += compute(buf, tr == tc);
    BARRIER();                                          // reads done before overwrite
    if (have_next && !samerow) {                        // rare: new row
      stageA(ntr);
      stageB(ntc, buf ^ 1);
    }
    tr = ntr; tc = ntc; buf ^= 1;
  }

  // ---- block reduction, one accum atomic, last-block finalize ----
#pragma unroll
  for (int off = 32; off > 0; off >>= 1) total += __shfl_down(total, off);
  if (lane == 0) red[wid] = total;
  __syncthreads();
  if (tid == 0) {
    float t = red[0] + red[1] + red[2] + red[3] + red[4] + red[5] + red[6] + red[7];
    atomicAdd(accum, t);
    __threadfence();
    unsigned int old = atomicAdd(counter, 1u);
    if (old == (unsigned int)(PBLOCKS - 1)) {
      float v = atomicAdd(accum, 0.f);  // coherent read of full sum
      out[0] = LN2F * (v * (1.0f / (float)N_DOCS) + 1.0f);
    }
  }
}

// fallback (ws too small): bf16-from-fp32 2-phase per-tile grid
__global__ __launch_bounds__(512, 2) void loss_fallback(const float* __restrict__ src,
                                                        float* __restrict__ accum) {
  const int b = blockIdx.x;
  int tr, tc;
  tri_decode(b, tr, tc);

  __shared__ alignas(16) unsigned short As[128 * 128];
  __shared__ alignas(16) unsigned short Bs[128 * 128];
  __shared__ float red[8];
  const int tid = threadIdx.x;

  const float4* srcA4 = (const float4*)(src + (size_t)tr * 16384);
  const float4* srcB4 = (const float4*)(src + (size_t)tc * 16384);
#pragma unroll
  for (int it = 0; it < 8; ++it) {
    int idx = it * 512 + tid;
    int L = idx * 8;
    int swz = L ^ (((L >> 8) & 7) << 4);
    float4 a = srcA4[idx];
    ushort4 oa = {f2bf(a.x * SQRT_LOG2E), f2bf(a.y * SQRT_LOG2E),
                  f2bf(a.z * SQRT_LOG2E), f2bf(a.w * SQRT_LOG2E)};
    *reinterpret_cast<ushort4*>((unsigned char*)As + swz) = oa;
    float4 bb = srcB4[idx];
    ushort4 ob = {f2bf(bb.x * SQRT_LOG2E), f2bf(bb.y * SQRT_LOG2E),
                  f2bf(bb.z * SQRT_LOG2E), f2bf(bb.w * SQRT_LOG2E)};
    *reinterpret_cast<ushort4*>((unsigned char*)Bs + swz) = ob;
  }
  __syncthreads();

  const int wid = tid >> 6;
  const int lane = tid & 63;
  const int wm = wid >> 2, wn = wid & 3;
  const int lrow = lane & 15;
  const int kgrp = lane >> 4;

  f32x4 acc[4][2];
#pragma unroll
  for (int a = 0; a < 4; ++a)
#pragma unroll
    for (int c = 0; c < 2; ++c) acc[a][c] = (f32x4){0.f, 0.f, 0.f, 0.f};

#pragma unroll
  for (int ks = 0; ks < 4; ++ks) {
    bf16x8 af[4], bfr[2];
#pragma unroll
    for (int f = 0; f < 4; ++f) {
      int ar = wm * 64 + f * 16 + lrow;
      int ab = (ar * 256 + ks * 64 + kgrp * 16) ^ ((ar & 7) << 4);
      af[f] = *reinterpret_cast<const bf16x8*>((const unsigned char*)As + ab);
    }
#pragma unroll
    for (int f = 0; f < 2; ++f) {
      int br = wn * 32 + f * 16 + lrow;
      int bb = (br * 256 + ks * 64 + kgrp * 16) ^ ((br & 7) << 4);
      bfr[f] = *reinterpret_cast<const bf16x8*>((const unsigned char*)Bs + bb);
    }
#pragma unroll
    for (int fm = 0; fm < 4; ++fm)
#pragma unroll
      for (int fn = 0; fn < 2; ++fn)
        acc[fm][fn] = __builtin_amdgcn_mfma_f32_16x16x32_bf16(af[fm], bfr[fn], acc[fm][fn], 0, 0, 0);
  }

  float sm = 0.f, sp = 0.f;
  if (tr == tc) {
#pragma unroll
    for (int fm = 0; fm < 4; ++fm)
#pragma unroll
      for (int fn = 0; fn < 2; ++fn)
#pragma unroll
        for (int r = 0; r < 4; ++r) {
          float v = acc[fm][fn][r];
          int il = wm * 64 + fm * 16 + kgrp * 4 + r;
          int jl = wn * 32 + fn * 16 + lrow;
          if (il == jl) v = -v;
          sm += fmaxf(v, 0.f);
          float u = EXP2F(-fabsf(v));
          sp = fmaf(u, fmaf(u, QC1, QC0), sp);
        }
  } else {
#pragma unroll
    for (int fm = 0; fm < 4; ++fm)
#pragma unroll
      for (int fn = 0; fn < 2; ++fn)
#pragma unroll
        for (int r = 0; r < 4; ++r) {
          float v = acc[fm][fn][r];
          sm += fmaxf(v, 0.f);
          float u = EXP2F(-fabsf(v));
          sp = fmaf(u, fmaf(u, QC1, QC0), sp);
        }
    sm *= 2.f;
    sp *= 2.f;
  }

  float lsum = sm + sp;
#pragma unroll
  for (int off = 32; off > 0; off >>= 1) lsum += __shfl_down(lsum, off);
  if (lane == 0) red[wid] = lsum;
  __syncthreads();
  if (tid == 0) {
    float t = red[0] + red[1] + red[2] + red[3] + red[4] + red[5] + red[6] + red[7];
    atomicAdd(accum, t);
  }
}

__global__ void finalize_kernel(const float* __restrict__ accum, float* __restrict__ out) {
  out[0] = LN2F * (accum[0] * (1.0f / (float)N_DOCS) + 1.0f);
}

extern "C" void kernel_launch(void* const* d_in, const int* in_sizes, int n_in,
                              void* d_out, int out_size, void* d_ws, size_t ws_size,
                              hipStream_t stream) {
  const float* E = (const float*)d_in[0];
  float* out = (float*)d_out;
  float* accum = (float*)d_ws;                                 // 4 B
  unsigned int* counter = (unsigned int*)((char*)d_ws + 64);   // 4 B

  const size_t need = 256 + (size_t)N_DOCS * DIM;  // ~2 MiB fp8 copy
  if (ws_size >= need) {
    unsigned char* ef8 = (unsigned char*)d_ws + 256;
    cast_kernel<<<(N_DOCS * (DIM / 8)) / 256, 256, 0, stream>>>(E, ef8, accum, counter);
    loss_persist<<<PBLOCKS, 512, 0, stream>>>(ef8, accum, counter, out);
  } else {
    (void)hipMemsetAsync(accum, 0, sizeof(float), stream);
    loss_fallback<<<NTRI, 512, 0, stream>>>(E, accum);
    finalize_kernel<<<1, 1, 0, stream>>>(accum, out);
  }
}

// Round 13
// 106.043 us; speedup vs baseline: 1.0167x; 1.0167x over previous
//
#include <hip/hip_runtime.h>
#include <hip/hip_bf16.h>

// loss = (1/N) * [ sum_i softplus(-s_ii) + sum_{i!=j} softplus(s_ij) ] + ln2
// S = E E^T, N=16384, D=128, scores in log2 domain (E pre-scaled sqrt(log2e)).
// ROUND 13: algebraic epilogue split. softplus_log2(v) = (v+|v|)/2 + P(2^-|v|).
// Over all ordered pairs: sum(v) = sum_k ColSum_k^2 (rank-1), diag flip = -R
// (R = sum of row norms). Both from cheap cast-phase reductions. The element
// loop keeps only the SIGN-INVARIANT part h = |v|/2 + u*(QC0+QC1*u), u=2^-|v|
// -> 5 instr, branch-free, no index math; diag tiles differ only by weight 1.
// T = accum + 0.5*sum(CS^2) - R;  loss = ln2*(T/N + 1).
// Structure from r12 (57 us, absmax 0): 768 persistent blocks (3/CU, 48KiB =
// A + B-dbuf), A-resident row-walk, counted vmcnt, fp8 e4m3 k-tiled layout,
// 16x16x32 fp8 MFMA, last-block finalize.

#define N_DOCS 16384
#define DIM 128
#define NTILE 128                      // N_DOCS / 128
#define NTRI (NTILE * (NTILE + 1) / 2) // 8256
#define PBLOCKS 768                    // persistent blocks, 3 per CU

typedef __attribute__((ext_vector_type(4))) float f32x4;
typedef __attribute__((ext_vector_type(8))) __bf16 bf16x8;   // fallback path
typedef __attribute__((ext_vector_type(2))) long longx2;

typedef const __attribute__((address_space(1))) unsigned char* gptr_t;
typedef __attribute__((address_space(3))) unsigned char* lptr_t;

#define SQRT_LOG2E 1.2011224087864498f
#define LN2F 0.6931471805599453f
// log2(1+u) ~= u*(QC0 + QC1*u) on [0,1]
#define QC0 1.33985f
#define QC1 (-0.33985f)

#if __has_builtin(__builtin_amdgcn_exp2f)
#define EXP2F(x) __builtin_amdgcn_exp2f(x)
#else
#define EXP2F(x) exp2f(x)
#endif

#define BARRIER() do { asm volatile("" ::: "memory"); \
                       __builtin_amdgcn_s_barrier();  \
                       asm volatile("" ::: "memory"); } while (0)

__device__ __forceinline__ unsigned short f2bf(float f) {
  unsigned int u = __float_as_uint(f);
  u += 0x7fffu + ((u >> 16) & 1u);
  return (unsigned short)(u >> 16);
}

#if __has_builtin(__builtin_amdgcn_cvt_pk_fp8_f32)
#define HAVE_CVT_FP8 1
#else
__device__ __forceinline__ unsigned char f2e4m3(float x) {
  unsigned int u = __float_as_uint(x);
  unsigned char sgn = (unsigned char)((u >> 31) << 7);
  float ax = fabsf(x);
  if (!(ax < 464.f)) return sgn | 0x7E;
  unsigned int ua = u & 0x7FFFFFFFu;
  int e = (int)(ua >> 23) - 127;
  if (e < -6) {
    float q = rintf(ax * 512.f);
    return sgn | (unsigned char)q;
  }
  unsigned int mant = ua & 0x7FFFFFu;
  unsigned int keep = mant >> 20;
  unsigned int rest = mant & 0xFFFFFu;
  keep += (rest > 0x80000u) || (rest == 0x80000u && (keep & 1u));
  unsigned int ee = (unsigned int)(e + 7);
  if (keep == 8u) { keep = 0u; ee++; }
  if (ee >= 16u) return sgn | 0x7E;
  return sgn | (unsigned char)((ee << 3) | keep);
}
#endif

__device__ __forceinline__ void tri_decode(int g, int& tr, int& tc) {
  int r = (int)((2 * NTILE + 1 -
                 sqrtf((float)((2 * NTILE + 1) * (2 * NTILE + 1)) - 8.0f * (float)g)) * 0.5f);
  while (r * NTILE - r * (r - 1) / 2 > g) --r;
  while ((r + 1) * NTILE - (r + 1) * r / 2 <= g) ++r;
  tr = r;
  tc = r + (g - (r * NTILE - r * (r - 1) / 2));
}

// f32 -> scaled fp8 (k-tiled layout) + per-slab colsum/rownorm partials.
// Grid: 128 blocks (one per 128-row slab) x 256 threads; thread = (rowgrp, kb),
// iterates 8 row-groups. Plain stores for partials -- NO atomics.
__global__ __launch_bounds__(256) void cast_kernel(const float* __restrict__ in,
                                                   unsigned char* __restrict__ out,
                                                   float* __restrict__ rpart,
                                                   float* __restrict__ colpart) {
  __shared__ float cs[16][136];  // [rowgrp][k], padded vs bank conflicts
  __shared__ float redr[4];
  const int b = blockIdx.x, tid = threadIdx.x;
  const int kb = tid & 15, rg = tid >> 4;

  float csum[8] = {0.f, 0.f, 0.f, 0.f, 0.f, 0.f, 0.f, 0.f};
  float rsum = 0.f;
#pragma unroll
  for (int it = 0; it < 8; ++it) {
    int r = it * 16 + rg;                       // row within slab
    int row = b * 128 + r;
    const float4* p = reinterpret_cast<const float4*>(in + (size_t)row * 128 + kb * 8);
    float4 a = p[0], c = p[1];
    float v0 = a.x * SQRT_LOG2E, v1 = a.y * SQRT_LOG2E, v2 = a.z * SQRT_LOG2E,
          v3 = a.w * SQRT_LOG2E, v4 = c.x * SQRT_LOG2E, v5 = c.y * SQRT_LOG2E,
          v6 = c.z * SQRT_LOG2E, v7 = c.w * SQRT_LOG2E;
    int w0, w1;
#ifdef HAVE_CVT_FP8
    w0 = __builtin_amdgcn_cvt_pk_fp8_f32(v0, v1, 0, false);
    w0 = __builtin_amdgcn_cvt_pk_fp8_f32(v2, v3, w0, true);
    w1 = __builtin_amdgcn_cvt_pk_fp8_f32(v4, v5, 0, false);
    w1 = __builtin_amdgcn_cvt_pk_fp8_f32(v6, v7, w1, true);
#else
    w0 = (int)f2e4m3(v0) | ((int)f2e4m3(v1) << 8) | ((int)f2e4m3(v2) << 16) | ((int)f2e4m3(v3) << 24);
    w1 = (int)f2e4m3(v4) | ((int)f2e4m3(v5) << 8) | ((int)f2e4m3(v6) << 16) | ((int)f2e4m3(v7) << 24);
#endif
    int g = kb & 3, s = kb >> 2;
    int off = b * 16384 + (g * 2 + (s >> 1)) * 2048 + r * 16 + (s & 1) * 8;
    *reinterpret_cast<int2*>(out + off) = make_int2(w0, w1);
    csum[0] += v0; csum[1] += v1; csum[2] += v2; csum[3] += v3;
    csum[4] += v4; csum[5] += v5; csum[6] += v6; csum[7] += v7;
    rsum = fmaf(v0, v0, rsum); rsum = fmaf(v1, v1, rsum);
    rsum = fmaf(v2, v2, rsum); rsum = fmaf(v3, v3, rsum);
    rsum = fmaf(v4, v4, rsum); rsum = fmaf(v5, v5, rsum);
    rsum = fmaf(v6, v6, rsum); rsum = fmaf(v7, v7, rsum);
  }
#pragma unroll
  for (int j = 0; j < 8; ++j) cs[rg][kb * 8 + j] = csum[j];
  // rownorm reduce (4 waves)
#pragma unroll
  for (int off = 32; off > 0; off >>= 1) rsum += __shfl_down(rsum, off);
  if ((tid & 63) == 0) redr[tid >> 6] = rsum;
  __syncthreads();
  if (tid < 128) {
    float s = 0.f;
#pragma unroll
    for (int r = 0; r < 16; ++r) s += cs[r][tid];
    colpart[b * 128 + tid] = s;
  }
  if (tid == 0) rpart[b] = redr[0] + redr[1] + redr[2] + redr[3];
}

__global__ __launch_bounds__(512, 6) void loss_persist(const unsigned char* __restrict__ ef8,
                                                       float* __restrict__ accum,
                                                       unsigned int* __restrict__ counter,
                                                       const float* __restrict__ rpart,
                                                       const float* __restrict__ colpart,
                                                       float* __restrict__ out) {
  __shared__ alignas(16) unsigned char Asl[16384];      // A slab (row-resident)
  __shared__ alignas(16) unsigned char Bsl[2][16384];   // B dbuf
  __shared__ float red[8];
  __shared__ int lastFlag;
  const int tid = threadIdx.x;
  const int p = blockIdx.x;
  const int g0 = (p * 43) >> 2;          // p * 8256/768
  const int g1 = ((p + 1) * 43) >> 2;
  const int n = g1 - g0;

  const int wid = tid >> 6;
  const int lane = tid & 63;
  const int wm = wid >> 2, wn = wid & 3;  // 2x4 waves: 64x32 output each
  const int lrow = lane & 15;
  const int kgrp = lane >> 4;

  auto stageA = [&](int t) {
    const unsigned char* s = ef8 + (size_t)t * 16384;
#pragma unroll
    for (int it = 0; it < 2; ++it) {
      int pp = (it * 512 + tid) * 16;
      __builtin_amdgcn_global_load_lds((gptr_t)(s + pp), (lptr_t)(Asl + pp), 16, 0, 0);
    }
  };
  auto stageB = [&](int t, int buf) {
    const unsigned char* s = ef8 + (size_t)t * 16384;
#pragma unroll
    for (int it = 0; it < 2; ++it) {
      int pp = (it * 512 + tid) * 16;
      __builtin_amdgcn_global_load_lds((gptr_t)(s + pp), (lptr_t)(Bsl[buf] + pp), 16, 0, 0);
    }
  };

  // branch-free: returns Sum over this thread's 32 elements of
  // |v|/2 + u*(QC0+QC1*u), u = 2^-|v|   (sign-invariant; diag needs no case)
  auto compute = [&](int buf) -> float {
    const unsigned char* As = (const unsigned char*)Asl;
    const unsigned char* Bs = (const unsigned char*)Bsl[buf];

    f32x4 acc[4][2];
#pragma unroll
    for (int a = 0; a < 4; ++a)
#pragma unroll
      for (int c = 0; c < 2; ++c) acc[a][c] = (f32x4){0.f, 0.f, 0.f, 0.f};

#pragma unroll
    for (int ks2 = 0; ks2 < 2; ++ks2) {
      longx2 af[4], bf[2];
      const int pbase = (kgrp * 2 + ks2) * 2048;
#pragma unroll
      for (int f = 0; f < 4; ++f) {
        int ar = wm * 64 + f * 16 + lrow;
        af[f] = *reinterpret_cast<const longx2*>(As + pbase + ar * 16);
      }
#pragma unroll
      for (int f = 0; f < 2; ++f) {
        int br = wn * 32 + f * 16 + lrow;
        bf[f] = *reinterpret_cast<const longx2*>(Bs + pbase + br * 16);
      }
#pragma unroll
      for (int fm = 0; fm < 4; ++fm)
#pragma unroll
        for (int fn = 0; fn < 2; ++fn) {
          acc[fm][fn] = __builtin_amdgcn_mfma_f32_16x16x32_fp8_fp8(af[fm].x, bf[fn].x,
                                                                   acc[fm][fn], 0, 0, 0);
          acc[fm][fn] = __builtin_amdgcn_mfma_f32_16x16x32_fp8_fp8(af[fm].y, bf[fn].y,
                                                                   acc[fm][fn], 0, 0, 0);
        }
    }

    float sa = 0.f, su = 0.f;
#pragma unroll
    for (int fm = 0; fm < 4; ++fm)
#pragma unroll
      for (int fn = 0; fn < 2; ++fn)
#pragma unroll
        for (int r = 0; r < 4; ++r) {
          float a = fabsf(acc[fm][fn][r]);
          sa += a;
          float u = EXP2F(-a);
          su = fmaf(u, fmaf(u, QC1, QC0), su);
        }
    return fmaf(0.5f, sa, su);
  };

  // ---- A-resident row-walk with B double-buffer ----
  int tr, tc;
  tri_decode(g0, tr, tc);
  float total = 0.f;
  int buf = 0;
  stageA(tr);
  stageB(tc, 0);
  for (int i = 0; i < n; ++i) {
    int ntr = tr, ntc = tc + 1;
    if (ntc == NTILE) { ntr = tr + 1; ntc = ntr; }
    const bool have_next = (i + 1 < n);
    const bool samerow = have_next && (ntr == tr);
    if (samerow) {
      stageB(ntc, buf ^ 1);
      asm volatile("s_waitcnt vmcnt(2)" ::: "memory");
    } else {
      asm volatile("s_waitcnt vmcnt(0)" ::: "memory");
    }
    BARRIER();
    total += (tr == tc ? 1.f : 2.f) * compute(buf);
    BARRIER();
    if (have_next && !samerow) {
      stageA(ntr);
      stageB(ntc, buf ^ 1);
    }
    tr = ntr; tc = ntc; buf ^= 1;
  }

  // ---- block reduction, one accum atomic, last-block finalize ----
#pragma unroll
  for (int off = 32; off > 0; off >>= 1) total += __shfl_down(total, off);
  if (lane == 0) red[wid] = total;
  __syncthreads();
  if (tid == 0) {
    float t = red[0] + red[1] + red[2] + red[3] + red[4] + red[5] + red[6] + red[7];
    atomicAdd(accum, t);
    __threadfence();
    unsigned int old = atomicAdd(counter, 1u);
    lastFlag = (old == (unsigned int)(PBLOCKS - 1));
  }
  __syncthreads();
  if (lastFlag) {
    // parallel: part_t = 0.5*CS_t^2 - rpart_t  (t < 128); sum -> scalar tail
    float part = 0.f;
    if (tid < 128) {
      float cs = 0.f;
#pragma unroll 8
      for (int b = 0; b < 128; ++b) cs += colpart[b * 128 + tid];
      part = fmaf(0.5f * cs, cs, -rpart[tid]);
    }
    if (tid < 128) {
#pragma unroll
      for (int off = 32; off > 0; off >>= 1) part += __shfl_down(part, off);
      if (lane == 0) red[wid] = part;
    }
    __syncthreads();
    if (tid == 0) {
      float tail = red[0] + red[1];
      float acc = atomicAdd(accum, 0.f);  // coherent read of full sum
      out[0] = LN2F * ((acc + tail) * (1.0f / (float)N_DOCS) + 1.0f);
    }
  }
}

// fallback (ws too small): bf16-from-fp32 2-phase per-tile grid (full softplus)
__global__ __launch_bounds__(512, 2) void loss_fallback(const float* __restrict__ src,
                                                        float* __restrict__ accum) {
  const int b = blockIdx.x;
  int tr, tc;
  tri_decode(b, tr, tc);

  __shared__ alignas(16) unsigned short As[128 * 128];
  __shared__ alignas(16) unsigned short Bs[128 * 128];
  __shared__ float red[8];
  const int tid = threadIdx.x;

  const float4* srcA4 = (const float4*)(src + (size_t)tr * 16384);
  const float4* srcB4 = (const float4*)(src + (size_t)tc * 16384);
#pragma unroll
  for (int it = 0; it < 8; ++it) {
    int idx = it * 512 + tid;
    int L = idx * 8;
    int swz = L ^ (((L >> 8) & 7) << 4);
    float4 a = srcA4[idx];
    ushort4 oa = {f2bf(a.x * SQRT_LOG2E), f2bf(a.y * SQRT_LOG2E),
                  f2bf(a.z * SQRT_LOG2E), f2bf(a.w * SQRT_LOG2E)};
    *reinterpret_cast<ushort4*>((unsigned char*)As + swz) = oa;
    float4 bb = srcB4[idx];
    ushort4 ob = {f2bf(bb.x * SQRT_LOG2E), f2bf(bb.y * SQRT_LOG2E),
                  f2bf(bb.z * SQRT_LOG2E), f2bf(bb.w * SQRT_LOG2E)};
    *reinterpret_cast<ushort4*>((unsigned char*)Bs + swz) = ob;
  }
  __syncthreads();

  const int wid = tid >> 6;
  const int lane = tid & 63;
  const int wm = wid >> 2, wn = wid & 3;
  const int lrow = lane & 15;
  const int kgrp = lane >> 4;

  f32x4 acc[4][2];
#pragma unroll
  for (int a = 0; a < 4; ++a)
#pragma unroll
    for (int c = 0; c < 2; ++c) acc[a][c] = (f32x4){0.f, 0.f, 0.f, 0.f};

#pragma unroll
  for (int ks = 0; ks < 4; ++ks) {
    bf16x8 af[4], bfr[2];
#pragma unroll
    for (int f = 0; f < 4; ++f) {
      int ar = wm * 64 + f * 16 + lrow;
      int ab = (ar * 256 + ks * 64 + kgrp * 16) ^ ((ar & 7) << 4);
      af[f] = *reinterpret_cast<const bf16x8*>((const unsigned char*)As + ab);
    }
#pragma unroll
    for (int f = 0; f < 2; ++f) {
      int br = wn * 32 + f * 16 + lrow;
      int bb = (br * 256 + ks * 64 + kgrp * 16) ^ ((br & 7) << 4);
      bfr[f] = *reinterpret_cast<const bf16x8*>((const unsigned char*)Bs + bb);
    }
#pragma unroll
    for (int fm = 0; fm < 4; ++fm)
#pragma unroll
      for (int fn = 0; fn < 2; ++fn)
        acc[fm][fn] = __builtin_amdgcn_mfma_f32_16x16x32_bf16(af[fm], bfr[fn], acc[fm][fn], 0, 0, 0);
  }

  float sm = 0.f, sp = 0.f;
  if (tr == tc) {
#pragma unroll
    for (int fm = 0; fm < 4; ++fm)
#pragma unroll
      for (int fn = 0; fn < 2; ++fn)
#pragma unroll
        for (int r = 0; r < 4; ++r) {
          float v = acc[fm][fn][r];
          int il = wm * 64 + fm * 16 + kgrp * 4 + r;
          int jl = wn * 32 + fn * 16 + lrow;
          if (il == jl) v = -v;
          sm += fmaxf(v, 0.f);
          float u = EXP2F(-fabsf(v));
          sp = fmaf(u, fmaf(u, QC1, QC0), sp);
        }
  } else {
#pragma unroll
    for (int fm = 0; fm < 4; ++fm)
#pragma unroll
      for (int fn = 0; fn < 2; ++fn)
#pragma unroll
        for (int r = 0; r < 4; ++r) {
          float v = acc[fm][fn][r];
          sm += fmaxf(v, 0.f);
          float u = EXP2F(-fabsf(v));
          sp = fmaf(u, fmaf(u, QC1, QC0), sp);
        }
    sm *= 2.f;
    sp *= 2.f;
  }

  float lsum = sm + sp;
#pragma unroll
  for (int off = 32; off > 0; off >>= 1) lsum += __shfl_down(lsum, off);
  if (lane == 0) red[wid] = lsum;
  __syncthreads();
  if (tid == 0) {
    float t = red[0] + red[1] + red[2] + red[3] + red[4] + red[5] + red[6] + red[7];
    atomicAdd(accum, t);
  }
}

__global__ void finalize_kernel(const float* __restrict__ accum, float* __restrict__ out) {
  out[0] = LN2F * (accum[0] * (1.0f / (float)N_DOCS) + 1.0f);
}

extern "C" void kernel_launch(void* const* d_in, const int* in_sizes, int n_in,
                              void* d_out, int out_size, void* d_ws, size_t ws_size,
                              hipStream_t stream) {
  const float* E = (const float*)d_in[0];
  float* out = (float*)d_out;
  float* accum = (float*)d_ws;                                  // @0
  unsigned int* counter = (unsigned int*)((char*)d_ws + 64);    // @64
  float* rpart = (float*)((char*)d_ws + 256);                   // @256, 512 B
  float* colpart = (float*)((char*)d_ws + 1024);                // @1024, 64 KiB
  unsigned char* ef8 = (unsigned char*)d_ws + 66560;            // @66560, 2 MiB

  const size_t need = 66560 + (size_t)N_DOCS * DIM + 256;
  if (ws_size >= need) {
    (void)hipMemsetAsync(d_ws, 0, 256, stream);  // accum + counter
    cast_kernel<<<128, 256, 0, stream>>>(E, ef8, rpart, colpart);
    loss_persist<<<PBLOCKS, 512, 0, stream>>>(ef8, accum, counter, rpart, colpart, out);
  } else {
    (void)hipMemsetAsync(accum, 0, sizeof(float), stream);
    loss_fallback<<<NTRI, 512, 0, stream>>>(E, accum);
    finalize_kernel<<<1, 1, 0, stream>>>(accum, out);
  }
}

// Round 14
// 100.815 us; speedup vs baseline: 1.0694x; 1.0519x over previous
//
#include <hip/hip_runtime.h>
#include <hip/hip_bf16.h>

// loss = (1/N) * [ sum_i softplus(-s_ii) + sum_{i!=j} softplus(s_ij) ] + ln2
// S = E E^T, N=16384, D=128, scores in log2 domain (E pre-scaled sqrt(log2e)).
// Algebraic split (r13): softplus_log2(v) = (v+|v|)/2 + P(2^-|v|); linear part
// = 0.5*sum_k ColSum_k^2 - R from cast-phase reductions; element loop keeps
// only h = |v|/2 + u*(QC0+QC1*u), u=2^-|v| (branch-free, sign-invariant).
// ROUND 14: MX-scaled MFMA. mfma_scale_f32_16x16x128_f8f6f4 does all K=128
// per fragment in ONE instr at 2x rate (identity E8M0 scales = 127 -> 2^0).
// k-permutation consistency: A and B lanes read the same chunk order, dot is
// permutation-invariant. 8 MFMA/thread-tile (was 16). setprio(1) around MFMA.
// Structure from r12/r13 (52 us, absmax 0): 768 persistent blocks (3/CU,
// 48KiB = A + B-dbuf), A-resident row-walk, counted vmcnt, fp8 k-tiled
// layout, last-block finalize. Memset folded into cast (one fewer dispatch).

#define N_DOCS 16384
#define DIM 128
#define NTILE 128                      // N_DOCS / 128
#define NTRI (NTILE * (NTILE + 1) / 2) // 8256
#define PBLOCKS 768                    // persistent blocks, 3 per CU

typedef __attribute__((ext_vector_type(4))) float f32x4;
typedef __attribute__((ext_vector_type(8))) __bf16 bf16x8;   // fallback path
typedef __attribute__((ext_vector_type(2))) long longx2;

typedef const __attribute__((address_space(1))) unsigned char* gptr_t;
typedef __attribute__((address_space(3))) unsigned char* lptr_t;

#define SQRT_LOG2E 1.2011224087864498f
#define LN2F 0.6931471805599453f
// log2(1+u) ~= u*(QC0 + QC1*u) on [0,1]
#define QC0 1.33985f
#define QC1 (-0.33985f)

#if __has_builtin(__builtin_amdgcn_exp2f)
#define EXP2F(x) __builtin_amdgcn_exp2f(x)
#else
#define EXP2F(x) exp2f(x)
#endif

#if __has_builtin(__builtin_amdgcn_mfma_scale_f32_16x16x128_f8f6f4)
#define HAVE_MX 1
typedef __attribute__((ext_vector_type(8))) int i32x8;
#endif

#define BARRIER() do { asm volatile("" ::: "memory"); \
                       __builtin_amdgcn_s_barrier();  \
                       asm volatile("" ::: "memory"); } while (0)

__device__ __forceinline__ unsigned short f2bf(float f) {
  unsigned int u = __float_as_uint(f);
  u += 0x7fffu + ((u >> 16) & 1u);
  return (unsigned short)(u >> 16);
}

#if __has_builtin(__builtin_amdgcn_cvt_pk_fp8_f32)
#define HAVE_CVT_FP8 1
#else
__device__ __forceinline__ unsigned char f2e4m3(float x) {
  unsigned int u = __float_as_uint(x);
  unsigned char sgn = (unsigned char)((u >> 31) << 7);
  float ax = fabsf(x);
  if (!(ax < 464.f)) return sgn | 0x7E;
  unsigned int ua = u & 0x7FFFFFFFu;
  int e = (int)(ua >> 23) - 127;
  if (e < -6) {
    float q = rintf(ax * 512.f);
    return sgn | (unsigned char)q;
  }
  unsigned int mant = ua & 0x7FFFFFu;
  unsigned int keep = mant >> 20;
  unsigned int rest = mant & 0xFFFFFu;
  keep += (rest > 0x80000u) || (rest == 0x80000u && (keep & 1u));
  unsigned int ee = (unsigned int)(e + 7);
  if (keep == 8u) { keep = 0u; ee++; }
  if (ee >= 16u) return sgn | 0x7E;
  return sgn | (unsigned char)((ee << 3) | keep);
}
#endif

__device__ __forceinline__ void tri_decode(int g, int& tr, int& tc) {
  int r = (int)((2 * NTILE + 1 -
                 sqrtf((float)((2 * NTILE + 1) * (2 * NTILE + 1)) - 8.0f * (float)g)) * 0.5f);
  while (r * NTILE - r * (r - 1) / 2 > g) --r;
  while ((r + 1) * NTILE - (r + 1) * r / 2 <= g) ++r;
  tr = r;
  tc = r + (g - (r * NTILE - r * (r - 1) / 2));
}

// f32 -> scaled fp8 (k-tiled layout) + per-slab colsum/rownorm partials.
// Also zeroes accum/counter (replaces memset dispatch; stream-ordered).
__global__ __launch_bounds__(256) void cast_kernel(const float* __restrict__ in,
                                                   unsigned char* __restrict__ out,
                                                   float* __restrict__ rpart,
                                                   float* __restrict__ colpart,
                                                   float* __restrict__ accum,
                                                   unsigned int* __restrict__ counter) {
  __shared__ float cs[16][136];
  __shared__ float redr[4];
  const int b = blockIdx.x, tid = threadIdx.x;
  const int kb = tid & 15, rg = tid >> 4;
  if (b == 0 && tid == 0) { accum[0] = 0.f; *counter = 0u; }

  float csum[8] = {0.f, 0.f, 0.f, 0.f, 0.f, 0.f, 0.f, 0.f};
  float rsum = 0.f;
#pragma unroll
  for (int it = 0; it < 8; ++it) {
    int r = it * 16 + rg;
    int row = b * 128 + r;
    const float4* p = reinterpret_cast<const float4*>(in + (size_t)row * 128 + kb * 8);
    float4 a = p[0], c = p[1];
    float v0 = a.x * SQRT_LOG2E, v1 = a.y * SQRT_LOG2E, v2 = a.z * SQRT_LOG2E,
          v3 = a.w * SQRT_LOG2E, v4 = c.x * SQRT_LOG2E, v5 = c.y * SQRT_LOG2E,
          v6 = c.z * SQRT_LOG2E, v7 = c.w * SQRT_LOG2E;
    int w0, w1;
#ifdef HAVE_CVT_FP8
    w0 = __builtin_amdgcn_cvt_pk_fp8_f32(v0, v1, 0, false);
    w0 = __builtin_amdgcn_cvt_pk_fp8_f32(v2, v3, w0, true);
    w1 = __builtin_amdgcn_cvt_pk_fp8_f32(v4, v5, 0, false);
    w1 = __builtin_amdgcn_cvt_pk_fp8_f32(v6, v7, w1, true);
#else
    w0 = (int)f2e4m3(v0) | ((int)f2e4m3(v1) << 8) | ((int)f2e4m3(v2) << 16) | ((int)f2e4m3(v3) << 24);
    w1 = (int)f2e4m3(v4) | ((int)f2e4m3(v5) << 8) | ((int)f2e4m3(v6) << 16) | ((int)f2e4m3(v7) << 24);
#endif
    int g = kb & 3, s = kb >> 2;
    int off = b * 16384 + (g * 2 + (s >> 1)) * 2048 + r * 16 + (s & 1) * 8;
    *reinterpret_cast<int2*>(out + off) = make_int2(w0, w1);
    csum[0] += v0; csum[1] += v1; csum[2] += v2; csum[3] += v3;
    csum[4] += v4; csum[5] += v5; csum[6] += v6; csum[7] += v7;
    rsum = fmaf(v0, v0, rsum); rsum = fmaf(v1, v1, rsum);
    rsum = fmaf(v2, v2, rsum); rsum = fmaf(v3, v3, rsum);
    rsum = fmaf(v4, v4, rsum); rsum = fmaf(v5, v5, rsum);
    rsum = fmaf(v6, v6, rsum); rsum = fmaf(v7, v7, rsum);
  }
#pragma unroll
  for (int j = 0; j < 8; ++j) cs[rg][kb * 8 + j] = csum[j];
#pragma unroll
  for (int off = 32; off > 0; off >>= 1) rsum += __shfl_down(rsum, off);
  if ((tid & 63) == 0) redr[tid >> 6] = rsum;
  __syncthreads();
  if (tid < 128) {
    float s = 0.f;
#pragma unroll
    for (int r = 0; r < 16; ++r) s += cs[r][tid];
    colpart[b * 128 + tid] = s;
  }
  if (tid == 0) rpart[b] = redr[0] + redr[1] + redr[2] + redr[3];
}

__global__ __launch_bounds__(512, 6) void loss_persist(const unsigned char* __restrict__ ef8,
                                                       float* __restrict__ accum,
                                                       unsigned int* __restrict__ counter,
                                                       const float* __restrict__ rpart,
                                                       const float* __restrict__ colpart,
                                                       float* __restrict__ out) {
  __shared__ alignas(16) unsigned char Asl[16384];
  __shared__ alignas(16) unsigned char Bsl[2][16384];
  __shared__ float red[8];
  __shared__ int lastFlag;
  const int tid = threadIdx.x;
  const int p = blockIdx.x;
  const int g0 = (p * 43) >> 2;
  const int g1 = ((p + 1) * 43) >> 2;
  const int n = g1 - g0;

  const int wid = tid >> 6;
  const int lane = tid & 63;
  const int wm = wid >> 2, wn = wid & 3;  // 2x4 waves: 64x32 output each
  const int lrow = lane & 15;
  const int kgrp = lane >> 4;

  auto stageA = [&](int t) {
    const unsigned char* s = ef8 + (size_t)t * 16384;
#pragma unroll
    for (int it = 0; it < 2; ++it) {
      int pp = (it * 512 + tid) * 16;
      __builtin_amdgcn_global_load_lds((gptr_t)(s + pp), (lptr_t)(Asl + pp), 16, 0, 0);
    }
  };
  auto stageB = [&](int t, int buf) {
    const unsigned char* s = ef8 + (size_t)t * 16384;
#pragma unroll
    for (int it = 0; it < 2; ++it) {
      int pp = (it * 512 + tid) * 16;
      __builtin_amdgcn_global_load_lds((gptr_t)(s + pp), (lptr_t)(Bsl[buf] + pp), 16, 0, 0);
    }
  };

  auto compute = [&](int buf) -> float {
    const unsigned char* As = (const unsigned char*)Asl;
    const unsigned char* Bs = (const unsigned char*)Bsl[buf];

    f32x4 acc[4][2];
#pragma unroll
    for (int a = 0; a < 4; ++a)
#pragma unroll
      for (int c = 0; c < 2; ++c) acc[a][c] = (f32x4){0.f, 0.f, 0.f, 0.f};

#ifdef HAVE_MX
    // K=128 in one MFMA per fragment. Lane (row, kgrp) reads chunks
    // P2 = 2*kgrp, 2*kgrp+1 (32 B); A and B use the same k-order ->
    // permutation-consistent dot. Identity scales (E8M0 127 = 2^0).
    const int pbase = kgrp * 2 * 2048;
    i32x8 b8[2];
#pragma unroll
    for (int f = 0; f < 2; ++f) {
      int br = wn * 32 + f * 16 + lrow;
      int4 lo = *reinterpret_cast<const int4*>(Bs + pbase + br * 16);
      int4 hi = *reinterpret_cast<const int4*>(Bs + pbase + 2048 + br * 16);
      b8[f] = (i32x8){lo.x, lo.y, lo.z, lo.w, hi.x, hi.y, hi.z, hi.w};
    }
    __builtin_amdgcn_s_setprio(1);
#pragma unroll
    for (int fm = 0; fm < 4; ++fm) {
      int ar = wm * 64 + fm * 16 + lrow;
      int4 lo = *reinterpret_cast<const int4*>(As + pbase + ar * 16);
      int4 hi = *reinterpret_cast<const int4*>(As + pbase + 2048 + ar * 16);
      i32x8 a8 = (i32x8){lo.x, lo.y, lo.z, lo.w, hi.x, hi.y, hi.z, hi.w};
#pragma unroll
      for (int fn = 0; fn < 2; ++fn)
        acc[fm][fn] = __builtin_amdgcn_mfma_scale_f32_16x16x128_f8f6f4(
            a8, b8[fn], acc[fm][fn], 0, 0, 0, 127, 0, 127);
    }
    __builtin_amdgcn_s_setprio(0);
#else
#pragma unroll
    for (int ks2 = 0; ks2 < 2; ++ks2) {
      longx2 af[4], bf[2];
      const int pbase = (kgrp * 2 + ks2) * 2048;
#pragma unroll
      for (int f = 0; f < 4; ++f) {
        int ar = wm * 64 + f * 16 + lrow;
        af[f] = *reinterpret_cast<const longx2*>(As + pbase + ar * 16);
      }
#pragma unroll
      for (int f = 0; f < 2; ++f) {
        int br = wn * 32 + f * 16 + lrow;
        bf[f] = *reinterpret_cast<const longx2*>(Bs + pbase + br * 16);
      }
      __builtin_amdgcn_s_setprio(1);
#pragma unroll
      for (int fm = 0; fm < 4; ++fm)
#pragma unroll
        for (int fn = 0; fn < 2; ++fn) {
          acc[fm][fn] = __builtin_amdgcn_mfma_f32_16x16x32_fp8_fp8(af[fm].x, bf[fn].x,
                                                                   acc[fm][fn], 0, 0, 0);
          acc[fm][fn] = __builtin_amdgcn_mfma_f32_16x16x32_fp8_fp8(af[fm].y, bf[fn].y,
                                                                   acc[fm][fn], 0, 0, 0);
        }
      __builtin_amdgcn_s_setprio(0);
    }
#endif

    float sa = 0.f, su = 0.f;
#pragma unroll
    for (int fm = 0; fm < 4; ++fm)
#pragma unroll
      for (int fn = 0; fn < 2; ++fn)
#pragma unroll
        for (int r = 0; r < 4; ++r) {
          float a = fabsf(acc[fm][fn][r]);
          sa += a;
          float u = EXP2F(-a);
          su = fmaf(u, fmaf(u, QC1, QC0), su);
        }
    return fmaf(0.5f, sa, su);
  };

  // ---- A-resident row-walk with B double-buffer ----
  int tr, tc;
  tri_decode(g0, tr, tc);
  float total = 0.f;
  int buf = 0;
  stageA(tr);
  stageB(tc, 0);
  for (int i = 0; i < n; ++i) {
    int ntr = tr, ntc = tc + 1;
    if (ntc == NTILE) { ntr = tr + 1; ntc = ntr; }
    const bool have_next = (i + 1 < n);
    const bool samerow = have_next && (ntr == tr);
    if (samerow) {
      stageB(ntc, buf ^ 1);
      asm volatile("s_waitcnt vmcnt(2)" ::: "memory");
    } else {
      asm volatile("s_waitcnt vmcnt(0)" ::: "memory");
    }
    BARRIER();
    total += (tr == tc ? 1.f : 2.f) * compute(buf);
    BARRIER();
    if (have_next && !samerow) {
      stageA(ntr);
      stageB(ntc, buf ^ 1);
    }
    tr = ntr; tc = ntc; buf ^= 1;
  }

  // ---- block reduction, one accum atomic, last-block finalize ----
#pragma unroll
  for (int off = 32; off > 0; off >>= 1) total += __shfl_down(total, off);
  if (lane == 0) red[wid] = total;
  __syncthreads();
  if (tid == 0) {
    float t = red[0] + red[1] + red[2] + red[3] + red[4] + red[5] + red[6] + red[7];
    atomicAdd(accum, t);
    __threadfence();
    unsigned int old = atomicAdd(counter, 1u);
    lastFlag = (old == (unsigned int)(PBLOCKS - 1));
  }
  __syncthreads();
  if (lastFlag) {
    float part = 0.f;
    if (tid < 128) {
      float cs = 0.f;
#pragma unroll 8
      for (int b = 0; b < 128; ++b) cs += colpart[b * 128 + tid];
      part = fmaf(0.5f * cs, cs, -rpart[tid]);
#pragma unroll
      for (int off = 32; off > 0; off >>= 1) part += __shfl_down(part, off);
      if (lane == 0) red[wid] = part;
    }
    __syncthreads();
    if (tid == 0) {
      float tail = red[0] + red[1];
      float acc = atomicAdd(accum, 0.f);
      out[0] = LN2F * ((acc + tail) * (1.0f / (float)N_DOCS) + 1.0f);
    }
  }
}

// fallback (ws too small): bf16-from-fp32 2-phase per-tile grid (full softplus)
__global__ __launch_bounds__(512, 2) void loss_fallback(const float* __restrict__ src,
                                                        float* __restrict__ accum) {
  const int b = blockIdx.x;
  int tr, tc;
  tri_decode(b, tr, tc);

  __shared__ alignas(16) unsigned short As[128 * 128];
  __shared__ alignas(16) unsigned short Bs[128 * 128];
  __shared__ float red[8];
  const int tid = threadIdx.x;

  const float4* srcA4 = (const float4*)(src + (size_t)tr * 16384);
  const float4* srcB4 = (const float4*)(src + (size_t)tc * 16384);
#pragma unroll
  for (int it = 0; it < 8; ++it) {
    int idx = it * 512 + tid;
    int L = idx * 8;
    int swz = L ^ (((L >> 8) & 7) << 4);
    float4 a = srcA4[idx];
    ushort4 oa = {f2bf(a.x * SQRT_LOG2E), f2bf(a.y * SQRT_LOG2E),
                  f2bf(a.z * SQRT_LOG2E), f2bf(a.w * SQRT_LOG2E)};
    *reinterpret_cast<ushort4*>((unsigned char*)As + swz) = oa;
    float4 bb = srcB4[idx];
    ushort4 ob = {f2bf(bb.x * SQRT_LOG2E), f2bf(bb.y * SQRT_LOG2E),
                  f2bf(bb.z * SQRT_LOG2E), f2bf(bb.w * SQRT_LOG2E)};
    *reinterpret_cast<ushort4*>((unsigned char*)Bs + swz) = ob;
  }
  __syncthreads();

  const int wid = tid >> 6;
  const int lane = tid & 63;
  const int wm = wid >> 2, wn = wid & 3;
  const int lrow = lane & 15;
  const int kgrp = lane >> 4;

  f32x4 acc[4][2];
#pragma unroll
  for (int a = 0; a < 4; ++a)
#pragma unroll
    for (int c = 0; c < 2; ++c) acc[a][c] = (f32x4){0.f, 0.f, 0.f, 0.f};

#pragma unroll
  for (int ks = 0; ks < 4; ++ks) {
    bf16x8 af[4], bfr[2];
#pragma unroll
    for (int f = 0; f < 4; ++f) {
      int ar = wm * 64 + f * 16 + lrow;
      int ab = (ar * 256 + ks * 64 + kgrp * 16) ^ ((ar & 7) << 4);
      af[f] = *reinterpret_cast<const bf16x8*>((const unsigned char*)As + ab);
    }
#pragma unroll
    for (int f = 0; f < 2; ++f) {
      int br = wn * 32 + f * 16 + lrow;
      int bb = (br * 256 + ks * 64 + kgrp * 16) ^ ((br & 7) << 4);
      bfr[f] = *reinterpret_cast<const bf16x8*>((const unsigned char*)Bs + bb);
    }
#pragma unroll
    for (int fm = 0; fm < 4; ++fm)
#pragma unroll
      for (int fn = 0; fn < 2; ++fn)
        acc[fm][fn] = __builtin_amdgcn_mfma_f32_16x16x32_bf16(af[fm], bfr[fn], acc[fm][fn], 0, 0, 0);
  }

  float sm = 0.f, sp = 0.f;
  if (tr == tc) {
#pragma unroll
    for (int fm = 0; fm < 4; ++fm)
#pragma unroll
      for (int fn = 0; fn < 2; ++fn)
#pragma unroll
        for (int r = 0; r < 4; ++r) {
          float v = acc[fm][fn][r];
          int il = wm * 64 + fm * 16 + kgrp * 4 + r;
          int jl = wn * 32 + fn * 16 + lrow;
          if (il == jl) v = -v;
          sm += fmaxf(v, 0.f);
          float u = EXP2F(-fabsf(v));
          sp = fmaf(u, fmaf(u, QC1, QC0), sp);
        }
  } else {
#pragma unroll
    for (int fm = 0; fm < 4; ++fm)
#pragma unroll
      for (int fn = 0; fn < 2; ++fn)
#pragma unroll
        for (int r = 0; r < 4; ++r) {
          float v = acc[fm][fn][r];
          sm += fmaxf(v, 0.f);
          float u = EXP2F(-fabsf(v));
          sp = fmaf(u, fmaf(u, QC1, QC0), sp);
        }
    sm *= 2.f;
    sp *= 2.f;
  }

  float lsum = sm + sp;
#pragma unroll
  for (int off = 32; off > 0; off >>= 1) lsum += __shfl_down(lsum, off);
  if (lane == 0) red[wid] = lsum;
  __syncthreads();
  if (tid == 0) {
    float t = red[0] + red[1] + red[2] + red[3] + red[4] + red[5] + red[6] + red[7];
    atomicAdd(accum, t);
  }
}

__global__ void finalize_kernel(const float* __restrict__ accum, float* __restrict__ out) {
  out[0] = LN2F * (accum[0] * (1.0f / (float)N_DOCS) + 1.0f);
}

extern "C" void kernel_launch(void* const* d_in, const int* in_sizes, int n_in,
                              void* d_out, int out_size, void* d_ws, size_t ws_size,
                              hipStream_t stream) {
  const float* E = (const float*)d_in[0];
  float* out = (float*)d_out;
  float* accum = (float*)d_ws;                                  // @0
  unsigned int* counter = (unsigned int*)((char*)d_ws + 64);    // @64
  float* rpart = (float*)((char*)d_ws + 256);                   // @256, 512 B
  float* colpart = (float*)((char*)d_ws + 1024);                // @1024, 64 KiB
  unsigned char* ef8 = (unsigned char*)d_ws + 66560;            // @66560, 2 MiB

  const size_t need = 66560 + (size_t)N_DOCS * DIM + 256;
  if (ws_size >= need) {
    cast_kernel<<<128, 256, 0, stream>>>(E, ef8, rpart, colpart, accum, counter);
    loss_persist<<<PBLOCKS, 512, 0, stream>>>(ef8, accum, counter, rpart, colpart, out);
  } else {
    (void)hipMemsetAsync(accum, 0, sizeof(float), stream);
    loss_fallback<<<NTRI, 512, 0, stream>>>(E, accum);
    finalize_kernel<<<1, 1, 0, stream>>>(accum, out);
  }
}